// Round 1
// baseline (489.887 us; speedup 1.0000x reference)
//
#include <hip/hip_runtime.h>

// Aggregate = column segment-sum: out[b][g] = sum_{c: sid[c]==g} x[b][c]
// x: [8192, 8192] f32, sid: [8192] i32 in [0,512), out: [8192, 512] f32.
//
// R1: LDS atomic scatter, 341us. R2: CSR gather 2-blk/CU, ~170us k_main:
//     barrier-serialized stage/gather phases, 8 waves/CU can't overlap.
// R3: row-pair + nontemporal, same structure -> same ~170us k_main.
// R4 (this): barrier-FREE single-wave blocks.
//     - 64-thr block = 1 wave, rowb[8192] f32 = 32KB LDS -> 5 blocks/CU.
//     - Stage row via global_load_lds (16B/lane, no VGPR roundtrip); only
//       sync is within-wave s_waitcnt vmcnt(0). Zero __syncthreads in k_main.
//     - Lane owns 8 groups (512/64): reads its CSR col span as u16 from
//       L2 (cols16 is 16KB, stays cache-hot), 1 random ds_read per element,
//       8 register accumulators, 32B coalesced nontemporal out store.
//     - Overlap across 5 independent waves/CU: stage-wait of one hides
//       under gather of others. HBM floor 272MB/6.3TBps = 43us.
//     - Prep fused to ONE single-block kernel (LDS hist+scan+scatter),
//       removes memset + 2 launches.

#define NCLS 8192
#define NGRP 512
#define TPB  64
#define GRID 1280   // 5 blocks/CU * 256 CU; grid-stride over rows

typedef float vf4 __attribute__((ext_vector_type(4)));

// d_ws layout (ints): offs[513] @0, cols16 (u16[8192] = 16KB) @1024

__global__ __launch_bounds__(512) void k_prep(const int* __restrict__ sid,
                                              int* __restrict__ offs,
                                              unsigned short* __restrict__ cols16) {
    __shared__ int hist[NGRP];
    __shared__ int tmp[NGRP];
    __shared__ int curs[NGRP];
    const int t = threadIdx.x;
    hist[t] = 0;
    __syncthreads();

    int g_[16];  // 8192 / 512 = 16 columns per thread, coalesced
#pragma unroll
    for (int i = 0; i < 16; ++i) {
        g_[i] = sid[t + 512 * i];
        atomicAdd(&hist[g_[i]], 1);
    }
    __syncthreads();

    const int h = hist[t];
    tmp[t] = h;
    __syncthreads();
    for (int off = 1; off < NGRP; off <<= 1) {
        int v = tmp[t];
        int u = (t >= off) ? tmp[t - off] : 0;
        __syncthreads();
        tmp[t] = v + u;
        __syncthreads();
    }
    const int excl = tmp[t] - h;  // exclusive prefix sum
    offs[t] = excl;
    curs[t] = excl;
    if (t == NGRP - 1) offs[NGRP] = NCLS;
    __syncthreads();

#pragma unroll
    for (int i = 0; i < 16; ++i) {
        int c = t + 512 * i;
        int pos = atomicAdd(&curs[g_[i]], 1);  // order within group irrelevant
        cols16[pos] = (unsigned short)c;
    }
}

__global__ __launch_bounds__(TPB) void k_main(const float* __restrict__ x,
                                              const unsigned short* __restrict__ cols16,
                                              const int* __restrict__ offs,
                                              float* __restrict__ out,
                                              int nrows) {
    __shared__ float rowb[NCLS];   // 32 KB -> 5 blocks/CU
    const int lane = threadIdx.x;  // 0..63, one wave per block
    const int g0 = lane * 8;       // this lane's 8 groups

    // Segment boundaries: row-invariant, hoisted. Static indexing -> registers.
    int o[9];
#pragma unroll
    for (int j = 0; j < 9; ++j) o[j] = offs[g0 + j];

    for (int row = blockIdx.x; row < nrows; row += GRID) {
        const float* xr = x + (size_t)row * NCLS;

        // Make sure last iteration's ds_reads are fully retired before the
        // async LDS writes below can land; also a compiler reorder fence.
        asm volatile("s_waitcnt lgkmcnt(0)" ::: "memory");

        // Stage row -> LDS: 32 x global_load_lds_dwordx4.
        // LDS dest = wave-uniform base + lane*16B (linear layout matches).
#pragma unroll
        for (int k = 0; k < 32; ++k) {
            __builtin_amdgcn_global_load_lds(
                (const __attribute__((address_space(1))) void*)(xr + k * 256 + lane * 4),
                (__attribute__((address_space(3))) void*)(&rowb[k * 256]),
                16, 0, 0);
        }
        asm volatile("s_waitcnt vmcnt(0)" ::: "memory");
        // Single wave: lockstep, no __syncthreads needed.

        float s[8];
#pragma unroll
        for (int j = 0; j < 8; ++j) {
            int p = o[j];
            const int e = o[j + 1];
            float a0 = 0.f, a1 = 0.f, a2 = 0.f, a3 = 0.f;
            for (; p + 4 <= e; p += 4) {
                int c0 = cols16[p];
                int c1 = cols16[p + 1];
                int c2 = cols16[p + 2];
                int c3 = cols16[p + 3];
                a0 += rowb[c0];
                a1 += rowb[c1];
                a2 += rowb[c2];
                a3 += rowb[c3];
            }
            for (; p < e; ++p) a0 += rowb[cols16[p]];
            s[j] = (a0 + a1) + (a2 + a3);
        }

        // 32B per lane, wave writes a contiguous 2KB out row: coalesced.
        vf4 a, b;
        a.x = s[0]; a.y = s[1]; a.z = s[2]; a.w = s[3];
        b.x = s[4]; b.y = s[5]; b.z = s[6]; b.w = s[7];
        float* op = out + (size_t)row * NGRP + g0;
        __builtin_nontemporal_store(a, reinterpret_cast<vf4*>(op));
        __builtin_nontemporal_store(b, reinterpret_cast<vf4*>(op + 4));
    }
}

extern "C" void kernel_launch(void* const* d_in, const int* in_sizes, int n_in,
                              void* d_out, int out_size, void* d_ws, size_t ws_size,
                              hipStream_t stream) {
    const float* x   = (const float*)d_in[0];
    const int*   sid = (const int*)d_in[1];
    float*       out = (float*)d_out;

    int* ws = (int*)d_ws;
    int* offs = ws;                                      // [513]
    unsigned short* cols16 = (unsigned short*)(ws + 1024);  // 16KB

    const int nrows = in_sizes[0] / NCLS;  // 8192

    k_prep<<<1, 512, 0, stream>>>(sid, offs, cols16);
    k_main<<<GRID, TPB, 0, stream>>>(x, cols16, offs, out, nrows);
}

// Round 2
// 435.054 us; speedup vs baseline: 1.1260x; 1.1260x over previous
//
#include <hip/hip_runtime.h>

// Aggregate = column segment-sum: out[b][g] = sum_{c: sid[c]==g} x[b][c]
// x: [8192, 8192] f32, sid: [8192] i32 in [0,512), out: [8192, 512] f32.
//
// R1: LDS atomic scatter, 341us. R2/R3: CSR gather, barrier-serialized, ~170us.
// R4: single-wave barrier-free blocks, 224us: cols16 read from GLOBAL per-lane
//     scattered -> 64 cacheline txns per load instr, L1 transaction-rate bound
//     (hbm 676 GB/s, VALU 5%, nothing saturated = latency serialization).
// R5 (this):
//     - colb[8192] u16 in LDS, DMA'd once per block (row-invariant, 16 rows
//       amortize it). Col reads are ds_read, PAIRED (aligned u32 = 2 indices).
//     - rowb[2][8192]: within-wave double buffer. Issue stage(row r+1) ->
//       gather row r from other buffer -> counted s_waitcnt vmcnt(2)
//       (32 stage loads are oldest; 2 newest are our output stores).
//       Stage latency hides under the gather; no wave ever idles on vmcnt(0)
//       except the prologue.
//     - 80KB LDS -> 2 blocks/CU; 512 blocks x 16 rows, no tail.
//     - HBM floor: 32 rows/CU * 32KB / 10.25 B/cyc = 102k cyc = 43us
//       (less with L3 absorbing ~half of x per R4's FETCH_SIZE=131MB).

#define NCLS 8192
#define NGRP 512
#define TPB  64
#define NBLK 512   // 2 blocks/CU * 256 CU
#define RPB  16    // rows per block

typedef float vf4 __attribute__((ext_vector_type(4)));

// d_ws layout (ints): offs[513] @0, cols16 (u16[8192] = 16KB) @1024

__global__ __launch_bounds__(512) void k_prep(const int* __restrict__ sid,
                                              int* __restrict__ offs,
                                              unsigned short* __restrict__ cols16) {
    __shared__ int hist[NGRP];
    __shared__ int tmp[NGRP];
    __shared__ int curs[NGRP];
    const int t = threadIdx.x;
    hist[t] = 0;
    __syncthreads();

    int g_[16];  // 8192 / 512 = 16 columns per thread, coalesced
#pragma unroll
    for (int i = 0; i < 16; ++i) {
        g_[i] = sid[t + 512 * i];
        atomicAdd(&hist[g_[i]], 1);
    }
    __syncthreads();

    const int h = hist[t];
    tmp[t] = h;
    __syncthreads();
    for (int off = 1; off < NGRP; off <<= 1) {
        int v = tmp[t];
        int u = (t >= off) ? tmp[t - off] : 0;
        __syncthreads();
        tmp[t] = v + u;
        __syncthreads();
    }
    const int excl = tmp[t] - h;  // exclusive prefix sum
    offs[t] = excl;
    curs[t] = excl;
    if (t == NGRP - 1) offs[NGRP] = NCLS;
    __syncthreads();

#pragma unroll
    for (int i = 0; i < 16; ++i) {
        int c = t + 512 * i;
        int pos = atomicAdd(&curs[g_[i]], 1);  // order within group irrelevant
        cols16[pos] = (unsigned short)c;
    }
}

__global__ __launch_bounds__(TPB) void k_main(const float* __restrict__ x,
                                              const unsigned short* __restrict__ cols16,
                                              const int* __restrict__ offs,
                                              float* __restrict__ out,
                                              int nrows) {
    __shared__ float rowb[2][NCLS];          // 64 KB: row double-buffer
    __shared__ unsigned short colb[NCLS];    // 16 KB: CSR column ids (u16)
    const int lane = threadIdx.x;            // 0..63, one wave per block
    const int g0 = lane * 8;                 // this lane's 8 groups
    const int row0 = blockIdx.x * RPB;

    // --- prologue: everything issued, then one vmcnt(0) ---
    // 1) CSR ids -> LDS: 16 x global_load_lds_dwordx4 (1KB/instr).
#pragma unroll
    for (int k = 0; k < 16; ++k) {
        __builtin_amdgcn_global_load_lds(
            (const __attribute__((address_space(1))) void*)(cols16 + k * 512 + lane * 8),
            (__attribute__((address_space(3))) void*)(&colb[k * 512]),
            16, 0, 0);
    }
    // 2) stage row0 -> rowb[0]
    {
        const float* xr = x + (size_t)row0 * NCLS;
#pragma unroll
        for (int k = 0; k < 32; ++k) {
            __builtin_amdgcn_global_load_lds(
                (const __attribute__((address_space(1))) void*)(xr + k * 256 + lane * 4),
                (__attribute__((address_space(3))) void*)(&rowb[0][k * 256]),
                16, 0, 0);
        }
    }
    // 3) segment boundaries (row-invariant): 2x int4 + 1 scalar, 32B-aligned.
    int o[9];
    {
        int4 q0 = *reinterpret_cast<const int4*>(offs + g0);
        int4 q1 = *reinterpret_cast<const int4*>(offs + g0 + 4);
        o[0] = q0.x; o[1] = q0.y; o[2] = q0.z; o[3] = q0.w;
        o[4] = q1.x; o[5] = q1.y; o[6] = q1.z; o[7] = q1.w;
        o[8] = offs[g0 + 8];
    }
    asm volatile("s_waitcnt vmcnt(0)" ::: "memory");

    int cur = 0;
    for (int r = 0; r < RPB; ++r) {
        const int row = row0 + r;

        // Issue next-row stage into the other buffer (fire, don't wait).
        if (r + 1 < RPB) {
            const float* xr = x + (size_t)(row + 1) * NCLS;
#pragma unroll
            for (int k = 0; k < 32; ++k) {
                __builtin_amdgcn_global_load_lds(
                    (const __attribute__((address_space(1))) void*)(xr + k * 256 + lane * 4),
                    (__attribute__((address_space(3))) void*)(&rowb[cur ^ 1][k * 256]),
                    16, 0, 0);
            }
        }

        // Gather current buffer. Col ids from LDS, paired u32 reads.
        const float* __restrict__ rb = rowb[cur];
        float s[8];
#pragma unroll
        for (int j = 0; j < 8; ++j) {
            int p = o[j];
            const int e = o[j + 1];
            float a0 = 0.f, a1 = 0.f, a2 = 0.f, a3 = 0.f;
            if ((p & 1) && p < e) {  // peel to u32 alignment
                a3 += rb[colb[p]];
                ++p;
            }
            for (; p + 4 <= e; p += 4) {
                unsigned cc0 = *reinterpret_cast<const unsigned*>(&colb[p]);
                unsigned cc1 = *reinterpret_cast<const unsigned*>(&colb[p + 2]);
                a0 += rb[cc0 & 0xffffu];
                a1 += rb[cc0 >> 16];
                a2 += rb[cc1 & 0xffffu];
                a3 += rb[cc1 >> 16];
            }
            if (p + 2 <= e) {
                unsigned cc0 = *reinterpret_cast<const unsigned*>(&colb[p]);
                a0 += rb[cc0 & 0xffffu];
                a1 += rb[cc0 >> 16];
                p += 2;
            }
            if (p < e) a2 += rb[colb[p]];
            s[j] = (a0 + a1) + (a2 + a3);
        }

        // 32B/lane, wave writes a contiguous 2KB out row: coalesced.
        vf4 a, b;
        a.x = s[0]; a.y = s[1]; a.z = s[2]; a.w = s[3];
        b.x = s[4]; b.y = s[5]; b.z = s[6]; b.w = s[7];
        float* op = out + (size_t)row * NGRP + g0;
        __builtin_nontemporal_store(a, reinterpret_cast<vf4*>(op));
        __builtin_nontemporal_store(b, reinterpret_cast<vf4*>(op + 4));

        // Wait for next-row stage: 32 stage loads are the OLDEST outstanding
        // vmem ops; the 2 newest are the stores above (fire-and-forget).
        if (r + 1 < RPB) {
            asm volatile("s_waitcnt vmcnt(2)" ::: "memory");
        }
        cur ^= 1;
    }
}

extern "C" void kernel_launch(void* const* d_in, const int* in_sizes, int n_in,
                              void* d_out, int out_size, void* d_ws, size_t ws_size,
                              hipStream_t stream) {
    const float* x   = (const float*)d_in[0];
    const int*   sid = (const int*)d_in[1];
    float*       out = (float*)d_out;

    int* ws = (int*)d_ws;
    int* offs = ws;                                         // [513]
    unsigned short* cols16 = (unsigned short*)(ws + 1024);  // 16KB

    const int nrows = in_sizes[0] / NCLS;  // 8192
    const int blocks = nrows / RPB;        // 512

    k_prep<<<1, 512, 0, stream>>>(sid, offs, cols16);
    k_main<<<blocks, TPB, 0, stream>>>(x, cols16, offs, out, nrows);
}